// Round 6
// baseline (74.366 us; speedup 1.0000x reference)
//
#include <hip/hip_runtime.h>

#define BG_OPACITY 1.0e10f
#define EPS_RM 1e-6f

typedef float nfloat4 __attribute__((ext_vector_type(4)));

// Layout (all float32):
//   d_in[0] rays_densities : (BR, 64)      BR = B*R = 262144
//   d_in[1] rays_features  : (BR, 64, 3)
//   d_in[2] ray_lengths    : (BR, 64)
//   d_in[3] bg_color       : (1,)
// d_out = [features (BR,3) | depth (BR,1) | opacities (BR,1) | weights (BR,64)]
//
// SURFACE_THICKNESS=1 collapse: absorption = [EPS+exp(-S), 1, 1, ..., 1]
// with S = sum_j delta_j * relu(rho_j). Only the per-ray total is needed.
//
// Structure: 16 lanes/ray (4 samples each via float4), 4 rays/wave,
// 2 ray-groups (8 rays) per wave. R5: NO grid-stride loop — exact grid,
// one pair per wave; block turnover provides the memory pipelining
// (fresh blocks issue load bursts while older waves sit in shuffle chains).
// Features NT-load (evict-first; keep 134 MB dens+len L3-resident);
// all stores NT (write-once).

__device__ __forceinline__ void process_group(
    int ray, int q, size_t rbase, size_t fbase,
    const float4* __restrict__ dens4,
    const nfloat4* __restrict__ feat4,
    const float4* __restrict__ len4,
    float bg,
    float* __restrict__ out_feat,
    float* __restrict__ out_depth,
    float* __restrict__ out_opac,
    nfloat4* __restrict__ out_w4,
    bool valid)
{
    float4 dv = dens4[rbase + q];
    float4 lv = len4[rbase + q];
    nfloat4 f0 = __builtin_nontemporal_load(&feat4[fbase + 0]);
    nfloat4 f1 = __builtin_nontemporal_load(&feat4[fbase + 1]);
    nfloat4 f2 = __builtin_nontemporal_load(&feat4[fbase + 2]);

    float nlen = __shfl_down(lv.x, 1);
    float d0 = lv.y - lv.x;
    float d1 = lv.z - lv.y;
    float d2 = lv.w - lv.z;
    float d3 = (q < 15) ? (nlen - lv.w) : BG_OPACITY;

    float w0 = d0 * fmaxf(dv.x, 0.f);
    float w1 = d1 * fmaxf(dv.y, 0.f);
    float w2 = d2 * fmaxf(dv.z, 0.f);
    float w3 = d3 * fmaxf(dv.w, 0.f);

    float S = (w0 + w1) + (w2 + w3);
    #pragma unroll
    for (int m = 1; m < 16; m <<= 1) S += __shfl_xor(S, m);

    float c0 = 1.f - __expf(-w0);
    float c1 = 1.f - __expf(-w1);
    float c2 = 1.f - __expf(-w2);
    float c3 = 1.f - __expf(-w3);
    if (q == 0) c0 *= (EPS_RM + __expf(-S));

    if (valid) {
        nfloat4 wv = {c0, c1, c2, c3};
        __builtin_nontemporal_store(wv, &out_w4[rbase + q]);
    }

    float fx = c0 * f0.x + c1 * f0.w + c2 * f1.z + c3 * f2.y;
    float fy = c0 * f0.y + c1 * f1.x + c2 * f1.w + c3 * f2.z;
    float fz = c0 * f0.z + c1 * f1.y + c2 * f2.x + c3 * f2.w;
    float dp = c0 * lv.x + c1 * lv.y + c2 * lv.z + c3 * lv.w;

    #pragma unroll
    for (int m = 1; m < 16; m <<= 1) {
        fx += __shfl_xor(fx, m);
        fy += __shfl_xor(fy, m);
        fz += __shfl_xor(fz, m);
        dp += __shfl_xor(dp, m);
    }

    if (q == 0 && valid) {
        float opac  = 1.f - __expf(-S);
        float addbg = (1.f - opac) * bg;
        __builtin_nontemporal_store(fx + addbg, &out_feat[(size_t)ray * 3 + 0]);
        __builtin_nontemporal_store(fy + addbg, &out_feat[(size_t)ray * 3 + 1]);
        __builtin_nontemporal_store(fz + addbg, &out_feat[(size_t)ray * 3 + 2]);
        __builtin_nontemporal_store(dp,   &out_depth[ray]);
        __builtin_nontemporal_store(opac, &out_opac[ray]);
    }
}

__global__ __launch_bounds__(256) void raymarch_kernel(
    const float4* __restrict__ dens4,
    const nfloat4* __restrict__ feat4,
    const float4* __restrict__ len4,
    const float*  __restrict__ bgp,
    float*  __restrict__ out_feat,
    float*  __restrict__ out_depth,
    float*  __restrict__ out_opac,
    nfloat4* __restrict__ out_w4,
    int n_rays)
{
    const int lane   = threadIdx.x & 63;
    const int q      = lane & 15;
    const int rslot  = lane >> 4;
    const int wid    = (blockIdx.x * blockDim.x + threadIdx.x) >> 6;
    const float bg   = bgp[0];

    const int ngroups = (n_rays + 3) >> 2;      // 4 rays per wave-group

    const int g0 = wid * 2;
    const int g1 = wid * 2 + 1;
    if (g0 >= ngroups) return;

    int ray0 = g0 * 4 + rslot;
    int ray1 = g1 * 4 + rslot;
    bool v0 = ray0 < n_rays;
    bool v1 = (g1 < ngroups) && (ray1 < n_rays);
    // clamp for safe (converged) loads; stores are predicated
    int r0c = v0 ? ray0 : (n_rays - 1);
    int r1c = v1 ? ray1 : (n_rays - 1);

    size_t rb0 = (size_t)r0c * 16, fb0 = (size_t)r0c * 48 + (size_t)q * 3;
    size_t rb1 = (size_t)r1c * 16, fb1 = (size_t)r1c * 48 + (size_t)q * 3;

    process_group(r0c, q, rb0, fb0, dens4, feat4, len4, bg,
                  out_feat, out_depth, out_opac, out_w4, v0);
    process_group(r1c, q, rb1, fb1, dens4, feat4, len4, bg,
                  out_feat, out_depth, out_opac, out_w4, v1);
}

extern "C" void kernel_launch(void* const* d_in, const int* in_sizes, int n_in,
                              void* d_out, int out_size, void* d_ws, size_t ws_size,
                              hipStream_t stream) {
    const float4*  dens4 = (const float4*)d_in[0];
    const nfloat4* feat4 = (const nfloat4*)d_in[1];
    const float4*  len4  = (const float4*)d_in[2];
    const float*   bgp   = (const float*)d_in[3];

    const int n_rays = in_sizes[0] / 64;

    float* out = (float*)d_out;
    float*   out_feat  = out;
    float*   out_depth = out + (size_t)n_rays * 3;
    float*   out_opac  = out + (size_t)n_rays * 4;
    nfloat4* out_w4    = (nfloat4*)(out + (size_t)n_rays * 5);

    const int ngroups = (n_rays + 3) / 4;       // 4 rays per wave-group
    const int npairs  = (ngroups + 1) / 2;      // 2 groups per wave
    const int waves_per_block = 256 / 64;
    int blocks = (npairs + waves_per_block - 1) / waves_per_block;
    if (blocks < 1) blocks = 1;

    raymarch_kernel<<<blocks, 256, 0, stream>>>(
        dens4, feat4, len4, bgp,
        out_feat, out_depth, out_opac, out_w4, n_rays);
}

// Round 8
// 73.062 us; speedup vs baseline: 1.0178x; 1.0178x over previous
//
#include <hip/hip_runtime.h>

#define BG_OPACITY 1.0e10f
#define EPS_RM 1e-6f

typedef float nfloat4 __attribute__((ext_vector_type(4)));

// Layout (all float32):
//   d_in[0] rays_densities : (BR, 64)      BR = B*R = 262144
//   d_in[1] rays_features  : (BR, 64, 3)
//   d_in[2] ray_lengths    : (BR, 64)
//   d_in[3] bg_color       : (1,)
// d_out = [features (BR,3) | depth (BR,1) | opacities (BR,1) | weights (BR,64)]
//
// SURFACE_THICKNESS=1 collapse: absorption = [EPS+exp(-S), 1, 1, ..., 1]
// with S = sum_j delta_j * relu(rho_j). Only the per-ray total is needed.
//
// Structure: 16 lanes/ray (4 samples each via float4), 4 rays/wave,
// 2 ray-groups (8 rays) per loop trip, grid-stride (2048-block cap).
// Features NT-load (evict-first; keep 134 MB dens+len L3-resident);
// weights store NT.
// R6/R7: ALL cross-lane ops via DPP (VALU pipe) instead of __shfl_*
// (ds_bpermute, shared DS pipe). 16-lane butterfly: quad_perm[1032]=0xB1,
// quad_perm[2301]=0x4E, row_half_mirror=0x141, row_mirror=0x140.
// Neighbor fetch (shfl_down 1): row_shl:1 = 0x101  (NOT row_shr -- that
// pulls from lane i-1; R7 bugfix).

#define DPP_XADD(v, ctrl) \
    ((v) + __int_as_float(__builtin_amdgcn_update_dpp( \
        0, __float_as_int(v), (ctrl), 0xF, 0xF, true)))

#define REDUCE16(v) do {            \
    (v) = DPP_XADD((v), 0xB1);      \
    (v) = DPP_XADD((v), 0x4E);      \
    (v) = DPP_XADD((v), 0x141);     \
    (v) = DPP_XADD((v), 0x140);     \
} while (0)

__device__ __forceinline__ void process_group(
    int ray, int q, size_t rbase, size_t fbase,
    const float4* __restrict__ dens4,
    const nfloat4* __restrict__ feat4,
    const float4* __restrict__ len4,
    float bg,
    float* __restrict__ out_feat,
    float* __restrict__ out_depth,
    float* __restrict__ out_opac,
    nfloat4* __restrict__ out_w4,
    bool valid)
{
    float4 dv = dens4[rbase + q];
    float4 lv = len4[rbase + q];
    nfloat4 f0 = __builtin_nontemporal_load(&feat4[fbase + 0]);
    nfloat4 f1 = __builtin_nontemporal_load(&feat4[fbase + 1]);
    nfloat4 f2 = __builtin_nontemporal_load(&feat4[fbase + 2]);

    // next lane's first length: row_shl:1 (dest lane i <- src lane i+1)
    float nlen = __int_as_float(__builtin_amdgcn_update_dpp(
        0, __float_as_int(lv.x), 0x101, 0xF, 0xF, true));

    float d0 = lv.y - lv.x;
    float d1 = lv.z - lv.y;
    float d2 = lv.w - lv.z;
    float d3 = (q < 15) ? (nlen - lv.w) : BG_OPACITY;

    float w0 = d0 * fmaxf(dv.x, 0.f);
    float w1 = d1 * fmaxf(dv.y, 0.f);
    float w2 = d2 * fmaxf(dv.z, 0.f);
    float w3 = d3 * fmaxf(dv.w, 0.f);

    float S = (w0 + w1) + (w2 + w3);
    REDUCE16(S);

    float c0 = 1.f - __expf(-w0);
    float c1 = 1.f - __expf(-w1);
    float c2 = 1.f - __expf(-w2);
    float c3 = 1.f - __expf(-w3);
    if (q == 0) c0 *= (EPS_RM + __expf(-S));

    if (valid) {
        nfloat4 wv = {c0, c1, c2, c3};
        __builtin_nontemporal_store(wv, &out_w4[rbase + q]);
    }

    float fx = c0 * f0.x + c1 * f0.w + c2 * f1.z + c3 * f2.y;
    float fy = c0 * f0.y + c1 * f1.x + c2 * f1.w + c3 * f2.z;
    float fz = c0 * f0.z + c1 * f1.y + c2 * f2.x + c3 * f2.w;
    float dp = c0 * lv.x + c1 * lv.y + c2 * lv.z + c3 * lv.w;

    REDUCE16(fx);
    REDUCE16(fy);
    REDUCE16(fz);
    REDUCE16(dp);

    if (q == 0 && valid) {
        float opac  = 1.f - __expf(-S);
        float addbg = (1.f - opac) * bg;
        out_feat[(size_t)ray * 3 + 0] = fx + addbg;
        out_feat[(size_t)ray * 3 + 1] = fy + addbg;
        out_feat[(size_t)ray * 3 + 2] = fz + addbg;
        out_depth[ray] = dp;
        out_opac[ray]  = opac;
    }
}

__global__ __launch_bounds__(256) void raymarch_kernel(
    const float4* __restrict__ dens4,
    const nfloat4* __restrict__ feat4,
    const float4* __restrict__ len4,
    const float*  __restrict__ bgp,
    float*  __restrict__ out_feat,
    float*  __restrict__ out_depth,
    float*  __restrict__ out_opac,
    nfloat4* __restrict__ out_w4,
    int n_rays)
{
    const int lane   = threadIdx.x & 63;
    const int q      = lane & 15;
    const int rslot  = lane >> 4;
    const int wid    = (blockIdx.x * blockDim.x + threadIdx.x) >> 6;
    const int nwaves = (gridDim.x * blockDim.x) >> 6;
    const float bg   = bgp[0];

    const int ngroups = (n_rays + 3) >> 2;      // 4 rays per wave-group
    const int npairs  = (ngroups + 1) >> 1;     // 2 groups per loop trip

    for (int p = wid; p < npairs; p += nwaves) {
        const int g0 = p * 2;
        const int g1 = p * 2 + 1;

        int ray0 = g0 * 4 + rslot;
        int ray1 = g1 * 4 + rslot;
        bool v0 = ray0 < n_rays;
        bool v1 = (g1 < ngroups) && (ray1 < n_rays);
        // clamp for safe (converged) loads; stores are predicated
        int r0c = v0 ? ray0 : (n_rays - 1);
        int r1c = v1 ? ray1 : (n_rays - 1);

        size_t rb0 = (size_t)r0c * 16, fb0 = (size_t)r0c * 48 + (size_t)q * 3;
        size_t rb1 = (size_t)r1c * 16, fb1 = (size_t)r1c * 48 + (size_t)q * 3;

        process_group(r0c, q, rb0, fb0, dens4, feat4, len4, bg,
                      out_feat, out_depth, out_opac, out_w4, v0);
        process_group(r1c, q, rb1, fb1, dens4, feat4, len4, bg,
                      out_feat, out_depth, out_opac, out_w4, v1);
    }
}

extern "C" void kernel_launch(void* const* d_in, const int* in_sizes, int n_in,
                              void* d_out, int out_size, void* d_ws, size_t ws_size,
                              hipStream_t stream) {
    const float4*  dens4 = (const float4*)d_in[0];
    const nfloat4* feat4 = (const nfloat4*)d_in[1];
    const float4*  len4  = (const float4*)d_in[2];
    const float*   bgp   = (const float*)d_in[3];

    const int n_rays = in_sizes[0] / 64;

    float* out = (float*)d_out;
    float*   out_feat  = out;
    float*   out_depth = out + (size_t)n_rays * 3;
    float*   out_opac  = out + (size_t)n_rays * 4;
    nfloat4* out_w4    = (nfloat4*)(out + (size_t)n_rays * 5);

    const int ngroups = (n_rays + 3) / 4;
    const int npairs  = (ngroups + 1) / 2;
    const int waves_per_block = 256 / 64;
    int blocks = (npairs + waves_per_block - 1) / waves_per_block;
    if (blocks > 2048) blocks = 2048;
    if (blocks < 1) blocks = 1;

    raymarch_kernel<<<blocks, 256, 0, stream>>>(
        dens4, feat4, len4, bgp,
        out_feat, out_depth, out_opac, out_w4, n_rays);
}